// Round 4
// baseline (235.561 us; speedup 1.0000x reference)
//
#include <hip/hip_runtime.h>
#include <hip/hip_bf16.h>

// PositionalEncoding: out[b,s,d] = x[b,s,d] + pe[s,d]
//   pe[s,d] = sin(s / 10000^((d/2)/S)) if d even else cos(...)
// x: [B=8, S=4096, D=1024] float32.
//
// R1: per-thread 8-batch loop -> serialized loads (24 VGPR), 2.28 TB/s.
// R3: 1 float4/thread + NT store -> ~67 us (est). Single-load waves give no
//     per-wave MLP; 32768 short blocks stress dispatch; NT forces writes to HBM.
// R4: grid-stride x4 with stride = 2 batches: same (s,d) for all 4 -> one PE
//     computation; 4 loads as distinct vars -> 4 outstanding dwordx4/wave;
//     plain stores so L3 (256 MiB) can absorb the 128 MiB write stream.

#define PE_S 4096
#define PE_D 1024
#define N4      (8 * PE_S * PE_D / 4)     // 8,388,608 float4 elements
#define NTHREAD (N4 / 4)                  // 2,097,152 threads
#define STRIDE4 NTHREAD                   // float4 stride between iterations

typedef float f32x4 __attribute__((ext_vector_type(4)));

__global__ __launch_bounds__(256) void PositionalEncoding_84095459656362_kernel(
    const float* __restrict__ x, float* __restrict__ out) {
    const int i  = blockIdx.x * blockDim.x + threadIdx.x;   // [0, NTHREAD)
    const int d4 = (i & (PE_D / 4 - 1)) << 2;               // d base: 0..1020
    const int s  = (i >> 8) & (PE_S - 1);                   // sequence pos

    const f32x4* xp = (const f32x4*)x + i;
    f32x4* op = (f32x4*)out + i;

    // Issue all four loads before any dependent use (4 outstanding dwordx4).
    const f32x4 v0 = xp[0];
    const f32x4 v1 = xp[STRIDE4];
    const f32x4 v2 = xp[2 * STRIDE4];
    const f32x4 v3 = xp[3 * STRIDE4];

    // angle(k) = s * 10000^(-k/S) = s * exp2(k * c), c = -log2(10000)/4096
    const float c  = -0.0032440703857f;
    const float r1 = 0.99775390625f;                         // 10000^(-1/4096)
    const float a0 = (float)s * __builtin_exp2f((float)(d4 >> 1) * c);
    const float a1 = a0 * r1;

    float s0, c0, s1, c1;
    __sincosf(a0, &s0, &c0);   // d even -> sin, d odd -> cos
    __sincosf(a1, &s1, &c1);
    f32x4 pe;
    pe.x = s0; pe.y = c0; pe.z = s1; pe.w = c1;

    op[0]           = v0 + pe;
    op[STRIDE4]     = v1 + pe;
    op[2 * STRIDE4] = v2 + pe;
    op[3 * STRIDE4] = v3 + pe;
}

extern "C" void kernel_launch(void* const* d_in, const int* in_sizes, int n_in,
                              void* d_out, int out_size, void* d_ws, size_t ws_size,
                              hipStream_t stream) {
    const float* x = (const float*)d_in[0];
    float* out = (float*)d_out;
    PositionalEncoding_84095459656362_kernel<<<NTHREAD / 256, 256, 0, stream>>>(x, out);
}